// Round 1
// baseline (563.255 us; speedup 1.0000x reference)
//
#include <hip/hip_runtime.h>

#define NTOK 197
#define C 768
#define C3 2304
#define BM 128
#define BK 32
#define PK 40    // padded LDS pitch in bf16 units (80B) -> 2-way bank aliasing (free)
#define NT 13    // 13 * 16 = 208 >= 197

typedef __attribute__((ext_vector_type(4))) float f32x4;
typedef __attribute__((ext_vector_type(8))) short bf16x8;

__device__ __forceinline__ ushort f2bf(float f){
  uint u = __float_as_uint(f);
  u += 0x7fffu + ((u >> 16) & 1u);   // RNE
  return (ushort)(u >> 16);
}
__device__ __forceinline__ uint pack2(float a, float b){
  return (uint)f2bf(a) | ((uint)f2bf(b) << 16);
}
__device__ __forceinline__ float bfu2f(uint u){ return __uint_as_float(u << 16); }

// ---------------------------------------------------------------------------
// Kernel 1: routing conv1d on CLS token -> s[bt][3c] = conv + a_bias + 1
// grid (36 o-chunks of 64, 16 b), block 256.
// ---------------------------------------------------------------------------
__global__ __launch_bounds__(256)
void conv_scales(const float* __restrict__ x, const float* __restrict__ aw,
                 const float* __restrict__ ab, float* __restrict__ s_ws)
{
  __shared__ __align__(16) float cls[10][C];   // rows 0 and 9 are zero padding
  __shared__ float partial[64][4][8];
  const int oc  = blockIdx.x;   // 0..35
  const int b   = blockIdx.y;   // 0..15
  const int tid = threadIdx.x;

  // load CLS rows for t' = -1..8 (rows 1..8 real, 0 and 9 zero)
  for (int task = tid; task < 1920; task += 256){
    int row = task / 192, c4 = task % 192;
    float4 v = {0.f,0.f,0.f,0.f};
    if (row >= 1 && row <= 8)
      v = *reinterpret_cast<const float4*>(x + (size_t)(b*8 + row - 1)*NTOK*C + c4*4);
    *reinterpret_cast<float4*>(&cls[row][c4*4]) = v;
  }
  __syncthreads();

  const int ol = tid >> 2, part = tid & 3;   // 64 outputs x 4 K-parts
  const int o_full = oc*64 + ol;
  float acc[8];
  #pragma unroll
  for (int t=0;t<8;t++) acc[t]=0.f;
  const float* awrow = aw + (size_t)o_full*2304;   // a_weight[o][i][k], k fastest

  for (int i = part*192; i < part*192 + 192; i += 4){
    const float* ap = awrow + i*3;
    float4 a0 = *reinterpret_cast<const float4*>(ap);
    float4 a1 = *reinterpret_cast<const float4*>(ap+4);
    float4 a2 = *reinterpret_cast<const float4*>(ap+8);
    float awf[12] = {a0.x,a0.y,a0.z,a0.w, a1.x,a1.y,a1.z,a1.w, a2.x,a2.y,a2.z,a2.w};
    float4 cv[10];
    #pragma unroll
    for (int t=0;t<10;t++) cv[t] = *reinterpret_cast<const float4*>(&cls[t][i]);
    #pragma unroll
    for (int e=0;e<4;e++){
      float w0 = awf[e*3+0], w1 = awf[e*3+1], w2 = awf[e*3+2];
      #pragma unroll
      for (int t=0;t<8;t++){
        const float* c0 = reinterpret_cast<const float*>(&cv[t]);
        const float* c1 = reinterpret_cast<const float*>(&cv[t+1]);
        const float* c2 = reinterpret_cast<const float*>(&cv[t+2]);
        acc[t] += w0*c0[e] + w1*c1[e] + w2*c2[e];
      }
    }
  }
  #pragma unroll
  for (int t=0;t<8;t++) partial[ol][part][t] = acc[t];
  __syncthreads();

  for (int idx = tid; idx < 512; idx += 256){
    int o_l = idx >> 3, t = idx & 7;
    float v = partial[o_l][0][t] + partial[o_l][1][t]
            + partial[o_l][2][t] + partial[o_l][3][t]
            + ab[oc*64 + o_l] + 1.0f;
    s_ws[(size_t)(b*8 + t)*C3 + oc*64 + o_l] = v;
  }
}

// ---------------------------------------------------------------------------
// Kernel 2: fp32 -> bf16 (grid-stride over float4 chunks)
// ---------------------------------------------------------------------------
__global__ void cvt_bf16(const float* __restrict__ in, ushort* __restrict__ outp, int n4)
{
  int stride = gridDim.x * blockDim.x;
  for (int i = blockIdx.x*blockDim.x + threadIdx.x; i < n4; i += stride){
    float4 v = reinterpret_cast<const float4*>(in)[i];
    ushort4 o;
    o.x = f2bf(v.x); o.y = f2bf(v.y); o.z = f2bf(v.z); o.w = f2bf(v.w);
    reinterpret_cast<ushort4*>(outp)[i] = o;
  }
}

// ---------------------------------------------------------------------------
// Kernel 3: main scaled GEMM.
// block = (o_tile, g, bt); 512 threads = 8 waves; each wave: 16 rows x 13 n-frags.
// Out[o][n] = sum_k (W[o][k]*s[k]) * X[n][k]  (+ bias[o]*s[o])
// ---------------------------------------------------------------------------
template<bool XBF>
__global__ __launch_bounds__(512)
void gemm_kernel(const float* __restrict__ x, const ushort* __restrict__ xbf,
                 const ushort* __restrict__ wbf, const float* __restrict__ s_ws,
                 const float* __restrict__ bias, float* __restrict__ out)
{
  __shared__ __align__(16) ushort A_lds[BM*PK];      // W (scaled), [128][40]
  __shared__ __align__(16) ushort B_lds[208*PK];     // X, [208][40] (rows >=197 zero)
  const int ot  = blockIdx.x;   // 0..5
  const int g   = blockIdx.y;   // 0..2
  const int bt  = blockIdx.z;   // 0..127
  const int tid = threadIdx.x;
  const int w = tid >> 6, lane = tid & 63;
  const int l15 = lane & 15, lq = lane >> 4;

  const float*  srow  = s_ws + (size_t)bt*C3 + (size_t)g*C;
  const ushort* wrow  = wbf + ((size_t)g*C + (size_t)ot*BM)*C;
  const float*  xrow  = x   + (size_t)bt*NTOK*C;
  const ushort* xbrow = xbf + (size_t)bt*NTOK*C;

  f32x4 acc[NT];
  #pragma unroll
  for (int j=0;j<NT;j++) acc[j] = (f32x4){0.f,0.f,0.f,0.f};

  const int ar = tid >> 2, ac = tid & 3;   // A: 128 rows x 4 chunks of 8 bf16

  for (int k0 = 0; k0 < C; k0 += BK){
    // ---- stage A: scaled weight -> bf16 LDS (512 tasks = 512 threads)
    {
      uint4 wv = *reinterpret_cast<const uint4*>(wrow + (size_t)ar*C + k0 + ac*8);
      const float* sv = srow + k0 + ac*8;
      float4 s0 = *reinterpret_cast<const float4*>(sv);
      float4 s1 = *reinterpret_cast<const float4*>(sv+4);
      uint4 av;
      av.x = pack2(bfu2f(wv.x & 0xffffu)*s0.x, bfu2f(wv.x >> 16)*s0.y);
      av.y = pack2(bfu2f(wv.y & 0xffffu)*s0.z, bfu2f(wv.y >> 16)*s0.w);
      av.z = pack2(bfu2f(wv.z & 0xffffu)*s1.x, bfu2f(wv.z >> 16)*s1.y);
      av.w = pack2(bfu2f(wv.w & 0xffffu)*s1.z, bfu2f(wv.w >> 16)*s1.w);
      *reinterpret_cast<uint4*>(&A_lds[ar*PK + ac*8]) = av;
    }
    // ---- stage B: X rows -> bf16 LDS (832 tasks, 2 iters)
    #pragma unroll
    for (int it = 0; it < 2; ++it){
      int task = tid + it*512;
      if (task < 832){
        int r = task >> 2, cc = task & 3;
        uint4 bv = {0u,0u,0u,0u};
        if (r < NTOK){
          if (XBF){
            bv = *reinterpret_cast<const uint4*>(xbrow + (size_t)r*C + k0 + cc*8);
          } else {
            const float* p = xrow + (size_t)r*C + k0 + cc*8;
            float4 lo = *reinterpret_cast<const float4*>(p);
            float4 hi = *reinterpret_cast<const float4*>(p+4);
            bv.x = pack2(lo.x, lo.y); bv.y = pack2(lo.z, lo.w);
            bv.z = pack2(hi.x, hi.y); bv.w = pack2(hi.z, hi.w);
          }
        }
        *reinterpret_cast<uint4*>(&B_lds[r*PK + cc*8]) = bv;
      }
    }
    __syncthreads();

    // ---- MFMA: wave w owns rows [w*16, w*16+16), all 13 n-frags
    bf16x8 a = *reinterpret_cast<const bf16x8*>(&A_lds[(w*16 + l15)*PK + lq*8]);
    #pragma unroll
    for (int j=0;j<NT;j++){
      bf16x8 b = *reinterpret_cast<const bf16x8*>(&B_lds[(j*16 + l15)*PK + lq*8]);
      acc[j] = __builtin_amdgcn_mfma_f32_16x16x32_bf16(a, b, acc[j], 0, 0, 0);
    }
    __syncthreads();
  }

  // ---- epilogue: bias modulated by s at the OUTPUT channel index
  const int obase = ot*BM + w*16 + lq*4;   // o within group g
  float bs[4];
  #pragma unroll
  for (int r=0;r<4;r++)
    bs[r] = bias[g*C + obase + r] * srow[obase + r];
  #pragma unroll
  for (int j=0;j<NT;j++){
    int n = j*16 + l15;
    if (n < NTOK){
      #pragma unroll
      for (int r=0;r<4;r++)
        out[((size_t)bt*C3 + g*C + obase + r)*NTOK + n] = acc[j][r] + bs[r];
    }
  }
}

// ---------------------------------------------------------------------------
extern "C" void kernel_launch(void* const* d_in, const int* in_sizes, int n_in,
                              void* d_out, int out_size, void* d_ws, size_t ws_size,
                              hipStream_t stream)
{
  const float* x        = (const float*)d_in[0];
  const float* a_weight = (const float*)d_in[1];
  const float* a_bias   = (const float*)d_in[2];
  const float* weight   = (const float*)d_in[3];
  const float* bias     = (const float*)d_in[4];
  float* out = (float*)d_out;

  char* ws = (char*)d_ws;
  float*  s_ws = (float*)ws;                          // 128*2304 f32  = 1,179,648 B
  ushort* wbf  = (ushort*)(ws + 1179648);             // 2304*768 bf16 = 3,538,944 B
  ushort* xbf  = (ushort*)(ws + 4718592);             // 128*197*768 bf16 = 38,731,776 B
  const bool use_xbf = ws_size >= (size_t)43450368;

  conv_scales<<<dim3(36,16), 256, 0, stream>>>(x, a_weight, a_bias, s_ws);
  cvt_bf16<<<dim3(1728), 256, 0, stream>>>(weight, wbf, 442368);   // 2304*768/4
  if (use_xbf){
    cvt_bf16<<<dim3(4096), 256, 0, stream>>>(x, xbf, 4841472);     // 128*197*768/4
    gemm_kernel<true><<<dim3(6,3,128), 512, 0, stream>>>(x, xbf, wbf, s_ws, bias, out);
  } else {
    gemm_kernel<false><<<dim3(6,3,128), 512, 0, stream>>>(x, xbf, wbf, s_ws, bias, out);
  }
}